// Round 9
// baseline (77.690 us; speedup 1.0000x reference)
//
#include <hip/hip_runtime.h>
#include <math.h>

#define SIZE 512
#define NPTS 128

__global__ __launch_bounds__(256) void contour_mask_kernel(
    const float* __restrict__ contour, float* __restrict__ out)
{
    __shared__ float2 c[NPTS + 1];   // +1 sentinel: c[128] = c[0], no wrap

    const int tid = threadIdx.x;
    if (tid < NPTS)  c[tid]  = ((const float2*)contour)[tid];
    if (tid == NPTS) c[NPTS] = ((const float2*)contour)[0];
    __syncthreads();

    const int p = blockIdx.x * 256 + tid;
    const int i = p >> 9;         // row  (first meshgrid coord)
    const int j = p & (SIZE - 1); // col  (second meshgrid coord)

    const float mx = (float)i * (1.0f / SIZE);
    const float my = (float)j * (1.0f / SIZE);

    const float K    = 100000.0f;
    const float PI_F = 3.14159265358979f;
    const float HPI  = 1.57079632679490f;
    // reference's eps-clip on cos mapped to angle space (acos monotone)
    const float ANG_LO = 4.4721397e-3f;
    const float ANG_HI = 3.1371205f;
    // |cross| >= CTHR  =>  |tanh(K*cross) - sign(cross)| <= 1-tanh(6) = 1.2e-5
    const float CTHR = 6e-5f;

    float ax = c[0].x - mx;
    float ay = c[0].y - my;

    float acc0 = 0.0f, acc1 = 0.0f;   // 2 partials to relax the add chain

    for (int g = 0; g < NPTS / 8; ++g) {
        // ---- phase 1: 8 cross/dot pairs (branch-free) ----
        float cr[8], dt[8];
        #pragma unroll
        for (int k = 0; k < 8; ++k) {
            const float2 cn = c[g * 8 + k + 1];   // imm-offset ds_read_b64
            const float bx = cn.x - mx;
            const float by = cn.y - my;
            cr[k] = fmaf(ay, bx, -ax * by);       // diff.y*roll.x - diff.x*roll.y
            dt[k] = fmaf(ax, bx,  ay * by);
            ax = bx; ay = by;
        }

        // ---- phase 2: 8 independent angle chains (branch-free block) ----
        float a[8];
        #pragma unroll
        for (int k = 0; k < 8; ++k) {
            const float acr = fabsf(cr[k]), adt = fabsf(dt[k]);
            const float mn  = fminf(acr, adt);
            const float mxv = fmaxf(acr, adt);
            const float t   = mn * __builtin_amdgcn_rcpf(mxv);
            const float s2  = t * t;
            // atan(t) ~= t * P(t^2), deg-11 odd minimax on [0,1], |err|~1e-5
            float q = fmaf(-0.01172120f, s2, 0.05265332f);
            q = fmaf(q, s2, -0.11643287f);
            q = fmaf(q, s2,  0.19354346f);
            q = fmaf(q, s2, -0.33262347f);
            q = fmaf(q, s2,  0.99997726f);
            float an = t * q;
            an = (acr > adt)    ? (HPI  - an) : an;  // octant swap
            an = (dt[k] < 0.0f) ? (PI_F - an) : an;  // reflect to [0, pi]
            a[k] = __builtin_amdgcn_fmed3f(an, ANG_LO, ANG_HI);
        }

        // ---- one wave-uniform band test for the whole group ----
        const float m0 = fminf(fminf(fabsf(cr[0]), fabsf(cr[1])),
                               fminf(fabsf(cr[2]), fabsf(cr[3])));
        const float m1 = fminf(fminf(fabsf(cr[4]), fabsf(cr[5])),
                               fminf(fabsf(cr[6]), fabsf(cr[7])));
        const float cmin = fminf(m0, m1);

        if (__any(cmin < CTHR)) {
            // rare (~0.04% of group-waves): exact tanh via exp
            #pragma unroll
            for (int k = 0; k < 8; ++k) {
                const float e  = __expf(2.0f * K * cr[k]);
                const float sg = fmaf(-2.0f, __builtin_amdgcn_rcpf(e + 1.0f), 1.0f);
                if (k & 1) acc1 = fmaf(sg, a[k], acc1);
                else       acc0 = fmaf(sg, a[k], acc0);
            }
        } else {
            #pragma unroll
            for (int k = 0; k < 8; ++k) {
                const float sa = __builtin_copysignf(a[k], cr[k]);
                if (k & 1) acc1 += sa;
                else       acc0 += sa;
            }
        }
    }

    float r = (acc0 + acc1) * (1.0f / (2.0f * PI_F));
    out[p] = __builtin_amdgcn_fmed3f(r, 0.0f, 1.0f);
}

extern "C" void kernel_launch(void* const* d_in, const int* in_sizes, int n_in,
                              void* d_out, int out_size, void* d_ws, size_t ws_size,
                              hipStream_t stream) {
    const float* contour = (const float*)d_in[0];
    float* out = (float*)d_out;

    const int total = SIZE * SIZE;   // 262144
    const int block = 256;
    const int grid  = total / block; // 1024 blocks -> 4096 waves, 4/SIMD

    contour_mask_kernel<<<grid, block, 0, stream>>>(contour, out);
}

// Round 10
// 76.402 us; speedup vs baseline: 1.0168x; 1.0168x over previous
//
#include <hip/hip_runtime.h>
#include <math.h>

#define SIZE 512
#define NPTS 128
#define SEGS 64   // segments per thread; lane pairs (2k,2k+1) share a pixel

__global__ __launch_bounds__(256) void contour_mask_kernel(
    const float* __restrict__ contour, float* __restrict__ out)
{
    __shared__ float2 c[NPTS + 1];   // sentinel c[128] = c[0]

    const int tid = threadIdx.x;
    if (tid < NPTS)  c[tid]  = ((const float2*)contour)[tid];
    if (tid == NPTS) c[NPTS] = ((const float2*)contour)[0];
    __syncthreads();

    // 128 pixels per block; adjacent lanes split one pixel's 128 segments.
    const int lpix = tid >> 1;           // local pixel
    const int half = tid & 1;            // 0: segs [0,64), 1: segs [64,128)
    const int start = half * SEGS;

    const int p = blockIdx.x * 128 + lpix;
    const int i = p >> 9;                // row  (first meshgrid coord)
    const int j = p & (SIZE - 1);        // col  (second meshgrid coord)

    const float mx = (float)i * (1.0f / SIZE);
    const float my = (float)j * (1.0f / SIZE);

    const float K    = 100000.0f;
    const float PI_F = 3.14159265358979f;
    const float HPI  = 1.57079632679490f;
    // reference's eps-clip on cos mapped to angle space (acos monotone)
    const float ANG_LO = 4.4721397e-3f;
    const float ANG_HI = 3.1371205f;
    // |cross| >= CTHR  =>  |tanh(K*cross) - sign(cross)| <= 1-tanh(6) = 1.2e-5
    const float CTHR = 6e-5f;

    float ax = c[start].x - mx;
    float ay = c[start].y - my;

    float acc0 = 0.0f, acc1 = 0.0f;

    for (int g = 0; g < SEGS / 8; ++g) {
        // ---- phase 1: 8 cross/dot pairs ----
        float cr[8], dt[8];
        #pragma unroll
        for (int k = 0; k < 8; ++k) {
            const float2 cn = c[start + g * 8 + k + 1];
            const float bx = cn.x - mx;
            const float by = cn.y - my;
            cr[k] = fmaf(ay, bx, -ax * by);   // diff.y*roll.x - diff.x*roll.y
            dt[k] = fmaf(ax, bx,  ay * by);
            ax = bx; ay = by;
        }

        // ---- phase 2: 8 independent branch-free angle chains ----
        float a[8];
        #pragma unroll
        for (int k = 0; k < 8; ++k) {
            const float acr = fabsf(cr[k]), adt = fabsf(dt[k]);
            const float mn  = fminf(acr, adt);
            const float mxv = fmaxf(acr, adt);
            const float t   = mn * __builtin_amdgcn_rcpf(mxv);
            const float s2  = t * t;
            float q = fmaf(-0.01172120f, s2, 0.05265332f);
            q = fmaf(q, s2, -0.11643287f);
            q = fmaf(q, s2,  0.19354346f);
            q = fmaf(q, s2, -0.33262347f);
            q = fmaf(q, s2,  0.99997726f);
            float an = t * q;
            an = (acr > adt)    ? (HPI  - an) : an;
            an = (dt[k] < 0.0f) ? (PI_F - an) : an;
            a[k] = __builtin_amdgcn_fmed3f(an, ANG_LO, ANG_HI);
        }

        // ---- one wave-uniform band test per group ----
        const float m0 = fminf(fminf(fabsf(cr[0]), fabsf(cr[1])),
                               fminf(fabsf(cr[2]), fabsf(cr[3])));
        const float m1 = fminf(fminf(fabsf(cr[4]), fabsf(cr[5])),
                               fminf(fabsf(cr[6]), fabsf(cr[7])));
        if (__any(fminf(m0, m1) < CTHR)) {
            #pragma unroll
            for (int k = 0; k < 8; ++k) {
                const float e  = __expf(2.0f * K * cr[k]);
                const float sg = fmaf(-2.0f, __builtin_amdgcn_rcpf(e + 1.0f), 1.0f);
                if (k & 1) acc1 = fmaf(sg, a[k], acc1);
                else       acc0 = fmaf(sg, a[k], acc0);
            }
        } else {
            #pragma unroll
            for (int k = 0; k < 8; ++k) {
                const float sa = __builtin_copysignf(a[k], cr[k]);
                if (k & 1) acc1 += sa;
                else       acc0 += sa;
            }
        }
    }

    // combine the two half-sums of this pixel: adjacent lanes, no barrier
    float tot = acc0 + acc1;
    tot += __shfl_xor(tot, 1, 64);

    if (half == 0) {
        const float r = tot * (1.0f / (2.0f * PI_F));
        out[p] = __builtin_amdgcn_fmed3f(r, 0.0f, 1.0f);
    }
}

extern "C" void kernel_launch(void* const* d_in, const int* in_sizes, int n_in,
                              void* d_out, int out_size, void* d_ws, size_t ws_size,
                              hipStream_t stream) {
    const float* contour = (const float*)d_in[0];
    float* out = (float*)d_out;

    const int total = SIZE * SIZE;       // 262144 pixels
    const int block = 256;               // 128 px x 2 halves
    const int grid  = total / 128;       // 2048 blocks -> 8192 waves, 8/SIMD

    contour_mask_kernel<<<grid, block, 0, stream>>>(contour, out);
}

// Round 11
// 74.923 us; speedup vs baseline: 1.0369x; 1.0197x over previous
//
#include <hip/hip_runtime.h>
#include <math.h>

#define SIZE 512
#define NPTS 128

typedef float v2f __attribute__((ext_vector_type(2)));

__global__ __launch_bounds__(256) void contour_mask_kernel(
    const float* __restrict__ contour, float* __restrict__ out)
{
    __shared__ float2 c[NPTS + 1];   // sentinel c[128] = c[0]

    const int tid = threadIdx.x;
    if (tid < NPTS)  c[tid]  = ((const float2*)contour)[tid];
    if (tid == NPTS) c[NPTS] = ((const float2*)contour)[0];
    __syncthreads();

    const int p = blockIdx.x * 256 + tid;
    const int i = p >> 9;         // row  (first meshgrid coord)
    const int j = p & (SIZE - 1); // col  (second meshgrid coord)

    const float mx = (float)i * (1.0f / SIZE);
    const float my = (float)j * (1.0f / SIZE);

    const float K    = 100000.0f;
    const float PI_F = 3.14159265358979f;
    const float HPI  = 1.57079632679490f;
    // reference's eps-clip on cos mapped to angle space (acos monotone)
    const float ANG_LO = 4.4721397e-3f;
    const float ANG_HI = 3.1371205f;
    // |cross| >= CTHR  =>  |tanh(K*cross) - sign(cross)| <= 1-tanh(6) = 1.2e-5
    const float CTHR = 6e-5f;

    float ax = c[0].x - mx;
    float ay = c[0].y - my;

    float acc0 = 0.0f, acc1 = 0.0f;

    for (int g = 0; g < NPTS / 8; ++g) {
        const int base = g * 8;

        // ---- phase 1: 8 cross/dot pairs, packed 2-wide (v_pk_fma_f32) ----
        v2f CRv[4], DTv[4];
        #pragma unroll
        for (int jp = 0; jp < 4; ++jp) {
            const float2 cn0 = c[base + 2 * jp + 1];
            const float2 cn1 = c[base + 2 * jp + 2];
            const v2f BX = v2f{cn0.x, cn1.x} - mx;
            const v2f BY = v2f{cn0.y, cn1.y} - my;
            const v2f AX = v2f{ax, BX.x};         // carried-diff chain
            const v2f AY = v2f{ay, BY.x};
            CRv[jp] = AY * BX - AX * BY;          // diff.y*roll.x - diff.x*roll.y
            DTv[jp] = AX * BX + AY * BY;
            ax = BX.y; ay = BY.y;
        }

        // ---- phase 2: packed atan chains ----
        v2f Av[4];
        #pragma unroll
        for (int jp = 0; jp < 4; ++jp) {
            const v2f CR = CRv[jp], DT = DTv[jp];
            // min/max with abs folded into VOP3 src modifiers (scalar: no pk form)
            const float mn0 = fminf(fabsf(CR.x), fabsf(DT.x));
            const float mx0 = fmaxf(fabsf(CR.x), fabsf(DT.x));
            const float mn1 = fminf(fabsf(CR.y), fabsf(DT.y));
            const float mx1 = fmaxf(fabsf(CR.y), fabsf(DT.y));
            const v2f T = v2f{mn0, mn1} *
                          v2f{__builtin_amdgcn_rcpf(mx0), __builtin_amdgcn_rcpf(mx1)};
            const v2f S = T * T;
            // atan(t) ~= t * P(t^2), deg-11 odd minimax on [0,1] — 5 pk_fma
            v2f Q = S * -0.01172120f + 0.05265332f;
            Q = Q * S + -0.11643287f;
            Q = Q * S +  0.19354346f;
            Q = Q * S + -0.33262347f;
            Q = Q * S +  0.99997726f;
            const v2f A = T * Q;
            const v2f H = HPI - A;                // packed
            const float a0 = (fabsf(CR.x) > fabsf(DT.x)) ? H.x : A.x;
            const float a1 = (fabsf(CR.y) > fabsf(DT.y)) ? H.y : A.y;
            const v2f A1 = {a0, a1};
            const v2f P = PI_F - A1;              // packed
            const float b0 = (DT.x < 0.0f) ? P.x : A1.x;
            const float b1 = (DT.y < 0.0f) ? P.y : A1.y;
            Av[jp] = v2f{__builtin_amdgcn_fmed3f(b0, ANG_LO, ANG_HI),
                         __builtin_amdgcn_fmed3f(b1, ANG_LO, ANG_HI)};
        }

        // ---- one wave-uniform band test per group ----
        const float bm =
            fminf(fminf(fminf(fabsf(CRv[0].x), fabsf(CRv[0].y)),
                        fminf(fabsf(CRv[1].x), fabsf(CRv[1].y))),
                  fminf(fminf(fabsf(CRv[2].x), fabsf(CRv[2].y)),
                        fminf(fabsf(CRv[3].x), fabsf(CRv[3].y))));

        if (__any(bm < CTHR)) {
            // rare: exact tanh via exp
            #pragma unroll
            for (int jp = 0; jp < 4; ++jp) {
                const float e0 = __expf(2.0f * K * CRv[jp].x);
                const float e1 = __expf(2.0f * K * CRv[jp].y);
                const float s0 = fmaf(-2.0f, __builtin_amdgcn_rcpf(e0 + 1.0f), 1.0f);
                const float s1 = fmaf(-2.0f, __builtin_amdgcn_rcpf(e1 + 1.0f), 1.0f);
                acc0 = fmaf(s0, Av[jp].x, acc0);
                acc1 = fmaf(s1, Av[jp].y, acc1);
            }
        } else {
            #pragma unroll
            for (int jp = 0; jp < 4; ++jp) {
                acc0 += __builtin_copysignf(Av[jp].x, CRv[jp].x);
                acc1 += __builtin_copysignf(Av[jp].y, CRv[jp].y);
            }
        }
    }

    const float r = (acc0 + acc1) * (1.0f / (2.0f * PI_F));
    out[p] = __builtin_amdgcn_fmed3f(r, 0.0f, 1.0f);
}

extern "C" void kernel_launch(void* const* d_in, const int* in_sizes, int n_in,
                              void* d_out, int out_size, void* d_ws, size_t ws_size,
                              hipStream_t stream) {
    const float* contour = (const float*)d_in[0];
    float* out = (float*)d_out;

    const int total = SIZE * SIZE;   // 262144
    const int block = 256;
    const int grid  = total / block; // 1024 blocks -> 4096 waves, 4/SIMD

    contour_mask_kernel<<<grid, block, 0, stream>>>(contour, out);
}

// Round 12
// 73.487 us; speedup vs baseline: 1.0572x; 1.0195x over previous
//
#include <hip/hip_runtime.h>
#include <math.h>

#define SIZE 512
#define NPTS 128

__global__ __launch_bounds__(256) void contour_mask_kernel(
    const float* __restrict__ contour, float* __restrict__ out)
{
    __shared__ float2 c[NPTS + 1];   // sentinel c[128] = c[0]

    const int tid = threadIdx.x;
    if (tid < NPTS)  c[tid]  = ((const float2*)contour)[tid];
    if (tid == NPTS) c[NPTS] = ((const float2*)contour)[0];
    __syncthreads();

    const int p = blockIdx.x * 256 + tid;
    const int i = p >> 9;         // row  (first meshgrid coord)
    const int j = p & (SIZE - 1); // col  (second meshgrid coord)

    const float mx = (float)i * (1.0f / SIZE);
    const float my = (float)j * (1.0f / SIZE);

    const float K    = 100000.0f;
    const float PI_F = 3.14159265358979f;
    const float HPI  = 1.57079632679490f;
    const float INV2PI = 0.15915494309190f;
    // reference's eps-clip on cos mapped to angle space (acos monotone)
    const float ANG_LO = 4.4721397e-3f;
    const float ANG_HI = 3.1371205f;
    // |cross| >= CTHR  =>  |tanh(K*cross) - sign(cross)| <= 1-tanh(6) = 1.2e-5
    const float CTHR = 6e-5f;

    float ax = c[0].x - mx;
    float ay = c[0].y - my;

    float w    = 0.0f;   // signed crossing count, reference orientation
    float corr = 0.0f;   // sum of (tanh*clip(ang) - sign*ang) for banded groups

    #pragma unroll 1
    for (int g = 0; g < NPTS / 8; ++g) {
        const float gax = ax, gay = ay;    // group-start diff, for fallback
        float bmin = 1e30f;

        // ---- fast path: signed ray-crossing count (+x ray from P) ----
        #pragma unroll
        for (int k = 0; k < 8; ++k) {
            const float2 cn = c[g * 8 + k + 1];
            const float bx = cn.x - mx;
            const float by = cn.y - my;
            // cr = diff.y*roll.x - diff.x*roll.y (reference orientation)
            const float cr = fmaf(ay, bx, -ax * by);
            // w += [ay>0 & by<=0 & cr>0] - [ay<=0 & by>0 & cr<0]
            const bool inc = (ay >  0.0f) & (by <= 0.0f) & (cr > 0.0f);
            const bool dec = (ay <= 0.0f) & (by >  0.0f) & (cr < 0.0f);
            w += inc ? 1.0f : 0.0f;
            w -= dec ? 1.0f : 0.0f;
            bmin = fminf(bmin, fabsf(cr));
            ax = bx; ay = by;
        }

        // ---- rare path: exact tanh/clip correction for this group ----
        if (__any(bmin < CTHR)) {
            float fax = gax, fay = gay;
            #pragma unroll
            for (int k = 0; k < 8; ++k) {
                const float2 cn = c[g * 8 + k + 1];
                const float bx = cn.x - mx;
                const float by = cn.y - my;
                const float cr = fmaf(fay, bx, -fax * by);
                const float dt = fmaf(fax, bx,  fay * by);

                // unsigned angle = atan2(|cr|, dt) via octant-reduced poly
                const float acr = fabsf(cr), adt = fabsf(dt);
                const float mn  = fminf(acr, adt);
                const float mxv = fmaxf(acr, adt);
                const float t   = mn * __builtin_amdgcn_rcpf(mxv);
                const float s2  = t * t;
                float q = fmaf(-0.01172120f, s2, 0.05265332f);
                q = fmaf(q, s2, -0.11643287f);
                q = fmaf(q, s2,  0.19354346f);
                q = fmaf(q, s2, -0.33262347f);
                q = fmaf(q, s2,  0.99997726f);
                float an = t * q;
                an = (acr > adt) ? (HPI  - an) : an;
                an = (dt < 0.0f) ? (PI_F - an) : an;
                const float anc = __builtin_amdgcn_fmed3f(an, ANG_LO, ANG_HI);

                // exact tanh via exp (saturation exact)
                const float e  = __expf(2.0f * K * cr);
                const float th = fmaf(-2.0f, __builtin_amdgcn_rcpf(e + 1.0f), 1.0f);

                // corr += tanh*clip(ang) - sign(cr)*ang
                corr += fmaf(th, anc, -__builtin_copysignf(an, cr));

                fax = bx; fay = by;
            }
        }
    }

    const float r = fmaf(corr, INV2PI, w);
    out[p] = __builtin_amdgcn_fmed3f(r, 0.0f, 1.0f);
}

extern "C" void kernel_launch(void* const* d_in, const int* in_sizes, int n_in,
                              void* d_out, int out_size, void* d_ws, size_t ws_size,
                              hipStream_t stream) {
    const float* contour = (const float*)d_in[0];
    float* out = (float*)d_out;

    const int total = SIZE * SIZE;   // 262144
    const int block = 256;
    const int grid  = total / block; // 1024 blocks -> 4096 waves, 4/SIMD

    contour_mask_kernel<<<grid, block, 0, stream>>>(contour, out);
}